// Round 6
// baseline (777.910 us; speedup 1.0000x reference)
//
#include <hip/hip_runtime.h>

// Problem constants
#define N_NODES 20000
#define N_ATTRS 5000
#define IN_F    512
#define OUT_F   128
#define KP      5120          // N_ATTRS padded to 160 ksteps x 32
#define KSTEPS  160
#define WH2_PAD 5376          // wh2 allocation incl. zeroed pad
#define LOG2E   1.4426950408889634f

typedef _Float16 f16x8 __attribute__((ext_vector_type(8)));
typedef float    f32x4 __attribute__((ext_vector_type(4)));
typedef int      i32x4 __attribute__((ext_vector_type(4)));

__device__ __forceinline__ float fast_exp2(float x) {
    return __builtin_amdgcn_exp2f(x);
}

// ---------------------------------------------------------------------------
// Kernel 1: Wa1 = W @ a[:128], Wa2 = W @ a[128:], pre-scaled by log2(e);
// repack W into f16 MFMA B-fragment order.
// ---------------------------------------------------------------------------
__global__ __launch_bounds__(256) void prep_kernel(
    const float* __restrict__ W, const float* __restrict__ a,
    float* __restrict__ Wa1, float* __restrict__ Wa2, _Float16* __restrict__ Wp) {
    int gt = blockIdx.x * blockDim.x + threadIdx.x;
    if (gt < IN_F) {
        int k = gt;
        float s1 = 0.f, s2 = 0.f;
        for (int f = 0; f < OUT_F; ++f) {
            float w = W[k * OUT_F + f];
            s1 += w * a[f];
            s2 += w * a[OUT_F + f];
        }
        Wa1[k] = s1 * LOG2E;
        Wa2[k] = s2 * LOG2E;
    }
    for (int idx = gt; idx < IN_F * OUT_F; idx += gridDim.x * blockDim.x) {
        int j    = idx & 7;
        int lane = (idx >> 3) & 63;
        int nb   = (idx >> 9) & 7;
        int kb   = idx >> 12;
        int k = kb * 32 + (lane >> 4) * 8 + j;
        int n = nb * 16 + (lane & 15);
        Wp[idx] = (_Float16)W[k * OUT_F + n];
    }
}

// ---------------------------------------------------------------------------
// Kernel 2: wh1[i] = node_emb[i] . Wa1 ; wh2[j] = attr_emb[j] . Wa2
// ---------------------------------------------------------------------------
__global__ __launch_bounds__(256) void wh_kernel(
    const float* __restrict__ node_emb, const float* __restrict__ attr_emb,
    const float* __restrict__ Wa1, const float* __restrict__ Wa2,
    float* __restrict__ wh1, float* __restrict__ wh2) {
    int wave = threadIdx.x >> 6, lane = threadIdx.x & 63;
    int r = blockIdx.x * 4 + wave;   // grid = 6250 -> r in [0, 25000)
    const float* src;
    const float* vec;
    float* dst;
    if (r < N_NODES) {
        src = node_emb + (size_t)r * IN_F; vec = Wa1; dst = wh1 + r;
    } else {
        int r2 = r - N_NODES;
        src = attr_emb + (size_t)r2 * IN_F; vec = Wa2; dst = wh2 + r2;
    }
    float4 ra = *reinterpret_cast<const float4*>(src + lane * 8);
    float4 rb = *reinterpret_cast<const float4*>(src + lane * 8 + 4);
    const float* vp = vec + lane * 8;
    float s = ra.x * vp[0] + ra.y * vp[1] + ra.z * vp[2] + ra.w * vp[3]
            + rb.x * vp[4] + rb.y * vp[5] + rb.z * vp[6] + rb.w * vp[7];
#pragma unroll
    for (int off = 1; off < 64; off <<= 1) s += __shfl_xor(s, off, 64);
    if (lane == 0) *dst = s;
}

// ---------------------------------------------------------------------------
// Kernel 2b: maxwh2 = max_j wh2[j]; zero wh2 pad region. single block.
// ---------------------------------------------------------------------------
__global__ __launch_bounds__(256) void max_kernel(
    float* __restrict__ wh2, float* __restrict__ maxp) {
    __shared__ float red[4];
    int t = threadIdx.x;
    float m = -1e30f;
    for (int j = t; j < N_ATTRS; j += 256) m = fmaxf(m, wh2[j]);
    for (int j = N_ATTRS + t; j < WH2_PAD; j += 256) wh2[j] = 0.f;
#pragma unroll
    for (int off = 1; off < 64; off <<= 1) m = fmaxf(m, __shfl_xor(m, off, 64));
    int wave = t >> 6, lane = t & 63;
    if (lane == 0) red[wave] = m;
    __syncthreads();
    if (t == 0) *maxp = fmaxf(fmaxf(red[0], red[1]), fmaxf(red[2], red[3]));
}

// ---------------------------------------------------------------------------
// Kernel 3: V = attr_emb @ W  [5120(pad) x 128] f16 in B-fragment order:
// Vp[kk*4096 + nb*512 + lane*8 + jj] = V[kk*32 + (lane>>4)*8 + jj][nb*16 + (lane&15)]
// ---------------------------------------------------------------------------
__global__ __launch_bounds__(256) void attr_h_kernel(
    const float* __restrict__ attr_emb, const _Float16* __restrict__ Wp,
    _Float16* __restrict__ Vp) {
    int wave = threadIdx.x >> 6, lane = threadIdx.x & 63;
    int m = lane & 15, quad = lane >> 4;
    int j0 = (blockIdx.x * 4 + wave) * 16;  // grid = 80 -> j0 in [0, 5120)
    int j = j0 + m;
    bool valid = j < N_ATTRS;
    f32x4 acc[8];
#pragma unroll
    for (int nb = 0; nb < 8; ++nb)
#pragma unroll
        for (int t = 0; t < 4; ++t) acc[nb][t] = 0.f;
    const float* arow = attr_emb + (size_t)j * IN_F;
    for (int kk = 0; kk < IN_F / 32; ++kk) {
        f16x8 afrag;
        if (valid) {
            float4 ra = *reinterpret_cast<const float4*>(arow + kk * 32 + quad * 8);
            float4 rb = *reinterpret_cast<const float4*>(arow + kk * 32 + quad * 8 + 4);
            afrag[0] = (_Float16)ra.x; afrag[1] = (_Float16)ra.y;
            afrag[2] = (_Float16)ra.z; afrag[3] = (_Float16)ra.w;
            afrag[4] = (_Float16)rb.x; afrag[5] = (_Float16)rb.y;
            afrag[6] = (_Float16)rb.z; afrag[7] = (_Float16)rb.w;
        } else {
#pragma unroll
            for (int t = 0; t < 8; ++t) afrag[t] = (_Float16)0.f;
        }
        const _Float16* wbase = Wp + (size_t)(kk * 8) * 64 * 8;
#pragma unroll
        for (int nb = 0; nb < 8; ++nb) {
            f16x8 bfrag;
            __builtin_memcpy(&bfrag, wbase + (nb * 64 + lane) * 8, 16);
            acc[nb] = __builtin_amdgcn_mfma_f32_16x16x32_f16(afrag, bfrag, acc[nb], 0, 0, 0);
        }
    }
#pragma unroll
    for (int nb = 0; nb < 8; ++nb) {
#pragma unroll
        for (int reg = 0; reg < 4; ++reg) {
            int jr = j0 + quad * 4 + reg;
            int n = nb * 16 + m;
            float v = (jr < N_ATTRS) ? acc[nb][reg] : 0.f;  // zero the K padding
            size_t idx = ((size_t)((jr >> 5) * 8 + nb) * 64 +
                          (((jr >> 3) & 3) * 16 + m)) * 8 + (jr & 7);
            Vp[idx] = (_Float16)v;
        }
    }
}

// ---------------------------------------------------------------------------
// Kernel 4 (main): 16 rows/block, 4 waves K-split (40 ksteps each),
// BARRIER-FREE K-loop (A-frags built in registers, wave-private state).
// Software pipeline with correct vmcnt ordering: per kstep the issue order is
//   [p-compute] [8 bfrag loads] [w2 prefetch k+1] [feat prefetch k+4] [8 MFMA]
// so prefetches are the YOUNGEST outstanding loads — the MFMA's bfrag waits
// (vmcnt(4)) leave them in flight (~3-4 iterations of cover for HBM latency).
// Feat staging is a 4-deep circular register buffer (loop unrolled by 4).
// ---------------------------------------------------------------------------
__global__ __launch_bounds__(256, 4) void attn_kernel(
    const int* __restrict__ feat, const float* __restrict__ wh1,
    const float* __restrict__ wh2, const float* __restrict__ maxwh2,
    const _Float16* __restrict__ Vp, float* __restrict__ out) {
    __shared__ float accp[16 * 128];   // epilogue only (8 KB)
    __shared__ float rsums[16];

    int wave = threadIdx.x >> 6, lane = threadIdx.x & 63;
    int m = lane & 15, quad = lane >> 4;
    int i0 = blockIdx.x * 16;          // grid = 1250, 20000 = 1250*16 exactly
    int i = i0 + m;
    float wh1i = wh1[i];               // scaled by log2(e)
    float emax = wh1i + maxwh2[0];
    float Mi = fmaxf(emax, 0.2f * emax) - 12.f;   // f16 P in (0, 4096]
    const int* frow = feat + (size_t)i * N_ATTRS;

    f32x4 acc[8];
#pragma unroll
    for (int nb = 0; nb < 8; ++nb)
#pragma unroll
        for (int t = 0; t < 4; ++t) acc[nb][t] = 0.f;
    float s = 0.f;

    const int kk0 = wave * 40;         // this wave's global kstep base

    // ---- staging registers ----
    i32x4 fa[4], fb[4];                // feat, 4-deep circular
    float4 wa, wb;                     // wh2, 1-deep (L1-hot)

    // prologue: feat for local steps 0..3, wh2 for step 0
#pragma unroll
    for (int d = 0; d < 4; ++d) {
        int jb = (kk0 + d) * 32 + quad * 8;
        int o1 = min(jb, N_ATTRS - 4);
        int o2 = min(jb + 4, N_ATTRS - 4);
        fa[d] = *reinterpret_cast<const i32x4*>(frow + o1);
        fb[d] = *reinterpret_cast<const i32x4*>(frow + o2);
    }
    {
        int jb = kk0 * 32 + quad * 8;
        wa = *reinterpret_cast<const float4*>(wh2 + jb);
        wb = *reinterpret_cast<const float4*>(wh2 + jb + 4);
    }

    const _Float16* vb0 = Vp + (size_t)kk0 * 4096;

    for (int su = 0; su < 10; ++su) {
#pragma unroll
        for (int du = 0; du < 4; ++du) {
            int kl = su * 4 + du;              // local kstep 0..39
            int jbase = (kk0 + kl) * 32 + quad * 8;

            // ---- 1. p-compute from staged registers (no vmem) ----
            i32x4 f0 = fa[du], f1 = fb[du];
            float4 w2a = wa, w2b = wb;
            int   fi[8] = {f0.x, f0.y, f0.z, f0.w, f1.x, f1.y, f1.z, f1.w};
            float wv[8] = {w2a.x, w2a.y, w2a.z, w2a.w, w2b.x, w2b.y, w2b.z, w2b.w};
            f16x8 afrag;
#pragma unroll
            for (int t = 0; t < 8; ++t) {
                float e = wh1i + wv[t];
                float l = fmaxf(e, 0.2f * e);
                float p = fast_exp2(l - Mi);
                bool ok = (fi[t] > 0) && (jbase + t < N_ATTRS);
                p = ok ? p : 0.f;
                _Float16 ph = (_Float16)p;
                s += (float)ph;                // sum quantized p: weights sum to 1
                afrag[t] = ph;
            }

            // ---- 2. issue all 8 bfrag loads (L2-resident Vp) ----
            const _Float16* vb = vb0 + (size_t)kl * 4096;
            f16x8 bf[8];
#pragma unroll
            for (int nb = 0; nb < 8; ++nb)
                __builtin_memcpy(&bf[nb], vb + nb * 512 + lane * 8, 16);

            // ---- 3. w2 prefetch (k+1): younger than bfrags ----
            {
                int jb = (kk0 + kl + 1) * 32 + quad * 8;   // <= 5176+8 < WH2_PAD
                wa = *reinterpret_cast<const float4*>(wh2 + jb);
                wb = *reinterpret_cast<const float4*>(wh2 + jb + 4);
            }
            // ---- 4. feat prefetch (k+4): youngest outstanding loads ----
            {
                int jb = (kk0 + kl + 4) * 32 + quad * 8;
                int o1 = min(jb, N_ATTRS - 4);
                int o2 = min(jb + 4, N_ATTRS - 4);
                fa[du] = *reinterpret_cast<const i32x4*>(frow + o1);
                fb[du] = *reinterpret_cast<const i32x4*>(frow + o2);
            }

            // ---- 5. MFMA: bfrag waits leave prefetches in flight ----
#pragma unroll
            for (int nb = 0; nb < 8; ++nb)
                acc[nb] = __builtin_amdgcn_mfma_f32_16x16x32_f16(afrag, bf[nb], acc[nb], 0, 0, 0);
        }
    }

    // ---- row-sum across quads (lanes m, m+16, m+32, m+48 share row m) ----
    s += __shfl_xor(s, 16, 64);
    s += __shfl_xor(s, 32, 64);

    // ---- serialized cross-wave combine (4 barriers, epilogue-only) ----
#pragma unroll
    for (int w = 0; w < 4; ++w) {
        if (wave == w) {
            if (w == 0) {
#pragma unroll
                for (int nb = 0; nb < 8; ++nb)
#pragma unroll
                    for (int reg = 0; reg < 4; ++reg)
                        accp[(quad * 4 + reg) * 128 + nb * 16 + m] = acc[nb][reg];
                if (lane < 16) rsums[lane] = s;
            } else {
#pragma unroll
                for (int nb = 0; nb < 8; ++nb)
#pragma unroll
                    for (int reg = 0; reg < 4; ++reg)
                        accp[(quad * 4 + reg) * 128 + nb * 16 + m] += acc[nb][reg];
                if (lane < 16) rsums[lane] += s;
            }
        }
        __syncthreads();
    }

    // ---- normalize, ELU, store fp32 ----
    for (int o = threadIdx.x; o < 16 * 128; o += 256) {
        int lr = o >> 7, n = o & 127;
        float v = accp[lr * 128 + n];
        float rs = rsums[lr];
        rs = (rs > 0.f) ? rs : 1.f;
        float h = v / rs;
        float ov = (h > 0.f) ? h : (fast_exp2(h * LOG2E) - 1.f);
        out[(size_t)(i0 + lr) * OUT_F + n] = ov;
    }
}

// ---------------------------------------------------------------------------
extern "C" void kernel_launch(void* const* d_in, const int* in_sizes, int n_in,
                              void* d_out, int out_size, void* d_ws, size_t ws_size,
                              hipStream_t stream) {
    const float* node_emb = (const float*)d_in[0];  // fp32 [20000,512]
    const float* attr_emb = (const float*)d_in[1];  // fp32 [5000,512]
    const int*   feat     = (const int*)d_in[2];    // int32 [20000,5000]
    const float* W        = (const float*)d_in[3];  // fp32 [512,128]
    const float* a        = (const float*)d_in[4];  // fp32 [256,1]
    float*       out      = (float*)d_out;          // fp32 [20000,128]

    char* ws = (char*)d_ws;
    float*    Wa1 = (float*)(ws + 0);          // 512 f32
    float*    Wa2 = (float*)(ws + 4096);       // 512 f32
    float*    wh1 = (float*)(ws + 8192);       // 20000 f32 (ends 88192)
    float*    wh2 = (float*)(ws + 90112);      // 5376 f32 incl. zeroed pad (ends 111616)
    float*    mx  = (float*)(ws + 111616);     // 1 f32
    _Float16* Wp  = (_Float16*)(ws + 131072);  // 65536 f16 (ends 262144)
    _Float16* Vp  = (_Float16*)(ws + 262144);  // 5120*128 f16 (ends 1572864)

    prep_kernel<<<64, 256, 0, stream>>>(W, a, Wa1, Wa2, Wp);
    wh_kernel<<<6250, 256, 0, stream>>>(node_emb, attr_emb, Wa1, Wa2, wh1, wh2);
    max_kernel<<<1, 256, 0, stream>>>(wh2, mx);
    attr_h_kernel<<<80, 256, 0, stream>>>(attr_emb, Wp, Vp);
    attn_kernel<<<1250, 256, 0, stream>>>(feat, wh1, wh2, mx, Vp, out);
}

// Round 7
// 721.609 us; speedup vs baseline: 1.0780x; 1.0780x over previous
//
#include <hip/hip_runtime.h>

// Problem constants
#define N_NODES 20000
#define N_ATTRS 5000
#define IN_F    512
#define OUT_F   128
#define KP      5120          // N_ATTRS padded to 160 ksteps x 32
#define KSTEPS  160
#define WH2_PAD 5376          // wh2 allocation incl. pad
#define NEGBIG  -1e30f        // wh2 pad value: exp2 underflows to 0 -> self-masking K-tail
#define LOG2E   1.4426950408889634f

typedef _Float16 f16x8 __attribute__((ext_vector_type(8)));
typedef float    f32x4 __attribute__((ext_vector_type(4)));
typedef int      i32x4 __attribute__((ext_vector_type(4)));

__device__ __forceinline__ float fast_exp2(float x) {
    return __builtin_amdgcn_exp2f(x);
}

// ---------------------------------------------------------------------------
// Kernel 1: Wa1 = W @ a[:128], Wa2 = W @ a[128:], pre-scaled by log2(e);
// repack W into f16 MFMA B-fragment order.
// ---------------------------------------------------------------------------
__global__ __launch_bounds__(256) void prep_kernel(
    const float* __restrict__ W, const float* __restrict__ a,
    float* __restrict__ Wa1, float* __restrict__ Wa2, _Float16* __restrict__ Wp) {
    int gt = blockIdx.x * blockDim.x + threadIdx.x;
    if (gt < IN_F) {
        int k = gt;
        float s1 = 0.f, s2 = 0.f;
        for (int f = 0; f < OUT_F; ++f) {
            float w = W[k * OUT_F + f];
            s1 += w * a[f];
            s2 += w * a[OUT_F + f];
        }
        Wa1[k] = s1 * LOG2E;
        Wa2[k] = s2 * LOG2E;
    }
    for (int idx = gt; idx < IN_F * OUT_F; idx += gridDim.x * blockDim.x) {
        int j    = idx & 7;
        int lane = (idx >> 3) & 63;
        int nb   = (idx >> 9) & 7;
        int kb   = idx >> 12;
        int k = kb * 32 + (lane >> 4) * 8 + j;
        int n = nb * 16 + (lane & 15);
        Wp[idx] = (_Float16)W[k * OUT_F + n];
    }
}

// ---------------------------------------------------------------------------
// Kernel 2: wh1[i] = node_emb[i] . Wa1 ; wh2[j] = attr_emb[j] . Wa2
// ---------------------------------------------------------------------------
__global__ __launch_bounds__(256) void wh_kernel(
    const float* __restrict__ node_emb, const float* __restrict__ attr_emb,
    const float* __restrict__ Wa1, const float* __restrict__ Wa2,
    float* __restrict__ wh1, float* __restrict__ wh2) {
    int wave = threadIdx.x >> 6, lane = threadIdx.x & 63;
    int r = blockIdx.x * 4 + wave;   // grid = 6250 -> r in [0, 25000)
    const float* src;
    const float* vec;
    float* dst;
    if (r < N_NODES) {
        src = node_emb + (size_t)r * IN_F; vec = Wa1; dst = wh1 + r;
    } else {
        int r2 = r - N_NODES;
        src = attr_emb + (size_t)r2 * IN_F; vec = Wa2; dst = wh2 + r2;
    }
    float4 ra = *reinterpret_cast<const float4*>(src + lane * 8);
    float4 rb = *reinterpret_cast<const float4*>(src + lane * 8 + 4);
    const float* vp = vec + lane * 8;
    float s = ra.x * vp[0] + ra.y * vp[1] + ra.z * vp[2] + ra.w * vp[3]
            + rb.x * vp[4] + rb.y * vp[5] + rb.z * vp[6] + rb.w * vp[7];
#pragma unroll
    for (int off = 1; off < 64; off <<= 1) s += __shfl_xor(s, off, 64);
    if (lane == 0) *dst = s;
}

// ---------------------------------------------------------------------------
// Kernel 2b: maxwh2 = max_j wh2[j]; fill wh2 pad with NEGBIG (self-masking
// K-tail: exp2(score + NEGBIG - Mi) == 0). single block.
// ---------------------------------------------------------------------------
__global__ __launch_bounds__(256) void max_kernel(
    float* __restrict__ wh2, float* __restrict__ maxp) {
    __shared__ float red[4];
    int t = threadIdx.x;
    float m = -1e30f;
    for (int j = t; j < N_ATTRS; j += 256) m = fmaxf(m, wh2[j]);
    for (int j = N_ATTRS + t; j < WH2_PAD; j += 256) wh2[j] = NEGBIG;
#pragma unroll
    for (int off = 1; off < 64; off <<= 1) m = fmaxf(m, __shfl_xor(m, off, 64));
    int wave = t >> 6, lane = t & 63;
    if (lane == 0) red[wave] = m;
    __syncthreads();
    if (t == 0) *maxp = fmaxf(fmaxf(red[0], red[1]), fmaxf(red[2], red[3]));
}

// ---------------------------------------------------------------------------
// Kernel 3: V = attr_emb @ W  [5120(pad) x 128] f16 in B-fragment order:
// Vp[kk*4096 + nb*512 + lane*8 + jj] = V[kk*32 + (lane>>4)*8 + jj][nb*16 + (lane&15)]
// ---------------------------------------------------------------------------
__global__ __launch_bounds__(256) void attr_h_kernel(
    const float* __restrict__ attr_emb, const _Float16* __restrict__ Wp,
    _Float16* __restrict__ Vp) {
    int wave = threadIdx.x >> 6, lane = threadIdx.x & 63;
    int m = lane & 15, quad = lane >> 4;
    int j0 = (blockIdx.x * 4 + wave) * 16;  // grid = 80 -> j0 in [0, 5120)
    int j = j0 + m;
    bool valid = j < N_ATTRS;
    f32x4 acc[8];
#pragma unroll
    for (int nb = 0; nb < 8; ++nb)
#pragma unroll
        for (int t = 0; t < 4; ++t) acc[nb][t] = 0.f;
    const float* arow = attr_emb + (size_t)j * IN_F;
    for (int kk = 0; kk < IN_F / 32; ++kk) {
        f16x8 afrag;
        if (valid) {
            float4 ra = *reinterpret_cast<const float4*>(arow + kk * 32 + quad * 8);
            float4 rb = *reinterpret_cast<const float4*>(arow + kk * 32 + quad * 8 + 4);
            afrag[0] = (_Float16)ra.x; afrag[1] = (_Float16)ra.y;
            afrag[2] = (_Float16)ra.z; afrag[3] = (_Float16)ra.w;
            afrag[4] = (_Float16)rb.x; afrag[5] = (_Float16)rb.y;
            afrag[6] = (_Float16)rb.z; afrag[7] = (_Float16)rb.w;
        } else {
#pragma unroll
            for (int t = 0; t < 8; ++t) afrag[t] = (_Float16)0.f;
        }
        const _Float16* wbase = Wp + (size_t)(kk * 8) * 64 * 8;
#pragma unroll
        for (int nb = 0; nb < 8; ++nb) {
            f16x8 bfrag;
            __builtin_memcpy(&bfrag, wbase + (nb * 64 + lane) * 8, 16);
            acc[nb] = __builtin_amdgcn_mfma_f32_16x16x32_f16(afrag, bfrag, acc[nb], 0, 0, 0);
        }
    }
#pragma unroll
    for (int nb = 0; nb < 8; ++nb) {
#pragma unroll
        for (int reg = 0; reg < 4; ++reg) {
            int jr = j0 + quad * 4 + reg;
            int n = nb * 16 + m;
            float v = (jr < N_ATTRS) ? acc[nb][reg] : 0.f;  // zero the K padding
            size_t idx = ((size_t)((jr >> 5) * 8 + nb) * 64 +
                          (((jr >> 3) & 3) * 16 + m)) * 8 + (jr & 7);
            Vp[idx] = (_Float16)v;
        }
    }
}

// ---------------------------------------------------------------------------
// Kernel 4 (main): 16 rows/block, 4 waves K-split (40 ksteps each),
// barrier-free K-loop. EVERY global stream is register-double-buffered with
// correct vmcnt age ordering:
//   iter kl: [issue bf(kl+1)] [p-compute] [wh2(kl+1)] [feat(kl+4)] [MFMA bf(kl)]
// MFMA consumes bfrags issued one full iteration earlier; its vmcnt wait
// leaves this iteration's 12 loads in flight. K-tail self-masks via
// wh2 pad = NEGBIG (no per-element bounds check).
// ---------------------------------------------------------------------------
__global__ __launch_bounds__(256, 3) void attn_kernel(
    const int* __restrict__ feat, const float* __restrict__ wh1,
    const float* __restrict__ wh2, const float* __restrict__ maxwh2,
    const _Float16* __restrict__ Vp, float* __restrict__ out) {
    __shared__ float accp[16 * 128];   // epilogue only (8 KB)
    __shared__ float rsums[16];

    int wave = threadIdx.x >> 6, lane = threadIdx.x & 63;
    int m = lane & 15, quad = lane >> 4;
    int i0 = blockIdx.x * 16;          // grid = 1250, 20000 = 1250*16 exactly
    int i = i0 + m;
    float wh1i = wh1[i];               // scaled by log2(e)
    float emax = wh1i + maxwh2[0];
    float Mi = fmaxf(emax, 0.2f * emax) - 12.f;   // f16 P in (0, 4096]
    const int* frow = feat + (size_t)i * N_ATTRS;

    f32x4 acc[8];
#pragma unroll
    for (int nb = 0; nb < 8; ++nb)
#pragma unroll
        for (int t = 0; t < 4; ++t) acc[nb][t] = 0.f;
    float s = 0.f;

    const int kk0 = wave * 40;         // this wave's global kstep base
    const _Float16* vb0 = Vp + (size_t)kk0 * 4096;

    // ---- staging registers ----
    i32x4 fa[4], fb[4];                // feat, 4-deep circular
    float4 wa, wb;                     // wh2, 1-deep (L1-hot)
    f16x8 bf[2][8];                    // bfrag, 1-deep double buffer

    // prologue: feat steps 0..3, wh2 step 0, bfrag step 0
#pragma unroll
    for (int d = 0; d < 4; ++d) {
        int jb = (kk0 + d) * 32 + quad * 8;
        int o1 = min(jb, N_ATTRS - 4);
        int o2 = min(jb + 4, N_ATTRS - 4);
        fa[d] = *reinterpret_cast<const i32x4*>(frow + o1);
        fb[d] = *reinterpret_cast<const i32x4*>(frow + o2);
    }
    {
        int jb = kk0 * 32 + quad * 8;
        wa = *reinterpret_cast<const float4*>(wh2 + jb);
        wb = *reinterpret_cast<const float4*>(wh2 + jb + 4);
    }
#pragma unroll
    for (int nb = 0; nb < 8; ++nb)
        __builtin_memcpy(&bf[0][nb], vb0 + nb * 512 + lane * 8, 16);

#pragma unroll 4
    for (int kl = 0; kl < 40; ++kl) {
        int cur = kl & 1, nxt = cur ^ 1;

        // ---- 1. issue NEXT kstep's bfrag loads (before anything waits) ----
        {
            int kln = min(kl + 1, 39);               // clamp: harmless reload at end
            const _Float16* vbn = vb0 + (size_t)kln * 4096;
#pragma unroll
            for (int nb = 0; nb < 8; ++nb)
                __builtin_memcpy(&bf[nxt][nb], vbn + nb * 512 + lane * 8, 16);
        }

        // ---- 2. p-compute from staged registers ----
        i32x4 f0 = fa[kl & 3], f1 = fb[kl & 3];
        float4 w2a = wa, w2b = wb;
        int   fi[8] = {f0.x, f0.y, f0.z, f0.w, f1.x, f1.y, f1.z, f1.w};
        float wv[8] = {w2a.x, w2a.y, w2a.z, w2a.w, w2b.x, w2b.y, w2b.z, w2b.w};
        f16x8 afrag;
#pragma unroll
        for (int t = 0; t < 8; ++t) {
            float e = wh1i + wv[t];                  // pad cols: e ~ -1e30
            float l = fmaxf(e, 0.2f * e);
            float p = fast_exp2(l - Mi);             // pad cols: exp2(-huge) = 0
            p = (fi[t] > 0) ? p : 0.f;
            _Float16 ph = (_Float16)p;
            s += (float)ph;                          // sum quantized p
            afrag[t] = ph;
        }

        // ---- 3. wh2 prefetch (kl+1) ----
        {
            int jb = (kk0 + kl + 1) * 32 + quad * 8; // < WH2_PAD always
            wa = *reinterpret_cast<const float4*>(wh2 + jb);
            wb = *reinterpret_cast<const float4*>(wh2 + jb + 4);
        }
        // ---- 4. feat prefetch (kl+4): youngest outstanding ----
        {
            int jb = (kk0 + kl + 4) * 32 + quad * 8;
            int o1 = min(jb, N_ATTRS - 4);
            int o2 = min(jb + 4, N_ATTRS - 4);
            fa[kl & 3] = *reinterpret_cast<const i32x4*>(frow + o1);
            fb[kl & 3] = *reinterpret_cast<const i32x4*>(frow + o2);
        }

        // ---- 5. MFMA with bfrags issued ONE ITERATION AGO ----
#pragma unroll
        for (int nb = 0; nb < 8; ++nb)
            acc[nb] = __builtin_amdgcn_mfma_f32_16x16x32_f16(afrag, bf[cur][nb], acc[nb], 0, 0, 0);
    }

    // ---- row-sum across quads (lanes m, m+16, m+32, m+48 share row m) ----
    s += __shfl_xor(s, 16, 64);
    s += __shfl_xor(s, 32, 64);

    // ---- serialized cross-wave combine (4 barriers, epilogue-only) ----
#pragma unroll
    for (int w = 0; w < 4; ++w) {
        if (wave == w) {
            if (w == 0) {
#pragma unroll
                for (int nb = 0; nb < 8; ++nb)
#pragma unroll
                    for (int reg = 0; reg < 4; ++reg)
                        accp[(quad * 4 + reg) * 128 + nb * 16 + m] = acc[nb][reg];
                if (lane < 16) rsums[lane] = s;
            } else {
#pragma unroll
                for (int nb = 0; nb < 8; ++nb)
#pragma unroll
                    for (int reg = 0; reg < 4; ++reg)
                        accp[(quad * 4 + reg) * 128 + nb * 16 + m] += acc[nb][reg];
                if (lane < 16) rsums[lane] += s;
            }
        }
        __syncthreads();
    }

    // ---- normalize, ELU, store fp32 ----
    for (int o = threadIdx.x; o < 16 * 128; o += 256) {
        int lr = o >> 7, n = o & 127;
        float v = accp[lr * 128 + n];
        float rs = rsums[lr];
        rs = (rs > 0.f) ? rs : 1.f;
        float h = v / rs;
        float ov = (h > 0.f) ? h : (fast_exp2(h * LOG2E) - 1.f);
        out[(size_t)(i0 + lr) * OUT_F + n] = ov;
    }
}

// ---------------------------------------------------------------------------
extern "C" void kernel_launch(void* const* d_in, const int* in_sizes, int n_in,
                              void* d_out, int out_size, void* d_ws, size_t ws_size,
                              hipStream_t stream) {
    const float* node_emb = (const float*)d_in[0];  // fp32 [20000,512]
    const float* attr_emb = (const float*)d_in[1];  // fp32 [5000,512]
    const int*   feat     = (const int*)d_in[2];    // int32 [20000,5000]
    const float* W        = (const float*)d_in[3];  // fp32 [512,128]
    const float* a        = (const float*)d_in[4];  // fp32 [256,1]
    float*       out      = (float*)d_out;          // fp32 [20000,128]

    char* ws = (char*)d_ws;
    float*    Wa1 = (float*)(ws + 0);          // 512 f32
    float*    Wa2 = (float*)(ws + 4096);       // 512 f32
    float*    wh1 = (float*)(ws + 8192);       // 20000 f32 (ends 88192)
    float*    wh2 = (float*)(ws + 90112);      // 5376 f32 incl. NEGBIG pad (ends 111616)
    float*    mx  = (float*)(ws + 111616);     // 1 f32
    _Float16* Wp  = (_Float16*)(ws + 131072);  // 65536 f16 (ends 262144)
    _Float16* Vp  = (_Float16*)(ws + 262144);  // 5120*128 f16 (ends 1572864)

    prep_kernel<<<64, 256, 0, stream>>>(W, a, Wa1, Wa2, Wp);
    wh_kernel<<<6250, 256, 0, stream>>>(node_emb, attr_emb, Wa1, Wa2, wh1, wh2);
    max_kernel<<<1, 256, 0, stream>>>(wh2, mx);
    attr_h_kernel<<<80, 256, 0, stream>>>(attr_emb, Wp, Vp);
    attn_kernel<<<1250, 256, 0, stream>>>(feat, wh1, wh2, mx, Vp, out);
}

// Round 8
// 649.941 us; speedup vs baseline: 1.1969x; 1.1103x over previous
//
#include <hip/hip_runtime.h>

// Problem constants
#define N_NODES 20000
#define N_ATTRS 5000
#define IN_F    512
#define OUT_F   128
#define KP      5120          // padded K: 160 ksteps x 32
#define KSTEPS  160
#define NSS     80            // supersteps (2 ksteps each)
#define WH2_PAD 5376          // wh2 allocation incl. pad
#define NEGBIG  -1e30f        // wh2 pad: exp2 underflows to 0 -> self-masking tail
#define LOG2E   1.4426950408889634f

typedef _Float16 f16x8 __attribute__((ext_vector_type(8)));
typedef float    f32x4 __attribute__((ext_vector_type(4)));
typedef int      i32x4 __attribute__((ext_vector_type(4)));

__device__ __forceinline__ float fast_exp2(float x) {
    return __builtin_amdgcn_exp2f(x);
}

// async global->LDS DMA, 16 B per lane. LDS dest = wave-uniform base + lane*16.
__device__ __forceinline__ void async16(void* lds_dst, const void* gsrc) {
    __builtin_amdgcn_global_load_lds(
        (const __attribute__((address_space(1))) unsigned int*)gsrc,
        (__attribute__((address_space(3))) unsigned int*)lds_dst, 16, 0, 0);
}

// ---------------------------------------------------------------------------
// Kernel 1: Wa1 = W @ a[:128], Wa2 = W @ a[128:], pre-scaled by log2(e);
// repack W into f16 MFMA B-fragment order.
// ---------------------------------------------------------------------------
__global__ __launch_bounds__(256) void prep_kernel(
    const float* __restrict__ W, const float* __restrict__ a,
    float* __restrict__ Wa1, float* __restrict__ Wa2, _Float16* __restrict__ Wp) {
    int gt = blockIdx.x * blockDim.x + threadIdx.x;
    if (gt < IN_F) {
        int k = gt;
        float s1 = 0.f, s2 = 0.f;
        for (int f = 0; f < OUT_F; ++f) {
            float w = W[k * OUT_F + f];
            s1 += w * a[f];
            s2 += w * a[OUT_F + f];
        }
        Wa1[k] = s1 * LOG2E;
        Wa2[k] = s2 * LOG2E;
    }
    for (int idx = gt; idx < IN_F * OUT_F; idx += gridDim.x * blockDim.x) {
        int j    = idx & 7;
        int lane = (idx >> 3) & 63;
        int nb   = (idx >> 9) & 7;
        int kb   = idx >> 12;
        int k = kb * 32 + (lane >> 4) * 8 + j;
        int n = nb * 16 + (lane & 15);
        Wp[idx] = (_Float16)W[k * OUT_F + n];
    }
}

// ---------------------------------------------------------------------------
// Kernel 2: wh1[i] = node_emb[i] . Wa1 ; wh2[j] = attr_emb[j] . Wa2
// ---------------------------------------------------------------------------
__global__ __launch_bounds__(256) void wh_kernel(
    const float* __restrict__ node_emb, const float* __restrict__ attr_emb,
    const float* __restrict__ Wa1, const float* __restrict__ Wa2,
    float* __restrict__ wh1, float* __restrict__ wh2) {
    int wave = threadIdx.x >> 6, lane = threadIdx.x & 63;
    int r = blockIdx.x * 4 + wave;   // grid = 6250 -> r in [0, 25000)
    const float* src;
    const float* vec;
    float* dst;
    if (r < N_NODES) {
        src = node_emb + (size_t)r * IN_F; vec = Wa1; dst = wh1 + r;
    } else {
        int r2 = r - N_NODES;
        src = attr_emb + (size_t)r2 * IN_F; vec = Wa2; dst = wh2 + r2;
    }
    float4 ra = *reinterpret_cast<const float4*>(src + lane * 8);
    float4 rb = *reinterpret_cast<const float4*>(src + lane * 8 + 4);
    const float* vp = vec + lane * 8;
    float s = ra.x * vp[0] + ra.y * vp[1] + ra.z * vp[2] + ra.w * vp[3]
            + rb.x * vp[4] + rb.y * vp[5] + rb.z * vp[6] + rb.w * vp[7];
#pragma unroll
    for (int off = 1; off < 64; off <<= 1) s += __shfl_xor(s, off, 64);
    if (lane == 0) *dst = s;
}

// ---------------------------------------------------------------------------
// Kernel 2b: maxwh2 = max_j wh2[j]; fill wh2 pad with NEGBIG. single block.
// ---------------------------------------------------------------------------
__global__ __launch_bounds__(256) void max_kernel(
    float* __restrict__ wh2, float* __restrict__ maxp) {
    __shared__ float red[4];
    int t = threadIdx.x;
    float m = -1e30f;
    for (int j = t; j < N_ATTRS; j += 256) m = fmaxf(m, wh2[j]);
    for (int j = N_ATTRS + t; j < WH2_PAD; j += 256) wh2[j] = NEGBIG;
#pragma unroll
    for (int off = 1; off < 64; off <<= 1) m = fmaxf(m, __shfl_xor(m, off, 64));
    int wave = t >> 6, lane = t & 63;
    if (lane == 0) red[wave] = m;
    __syncthreads();
    if (t == 0) *maxp = fmaxf(fmaxf(red[0], red[1]), fmaxf(red[2], red[3]));
}

// ---------------------------------------------------------------------------
// Kernel 3: V = attr_emb @ W  [5120(pad) x 128] f16 in B-fragment order:
// Vp[kk*4096 + nb*512 + lane*8 + jj] = V[kk*32 + (lane>>4)*8 + jj][nb*16 + (lane&15)]
// ---------------------------------------------------------------------------
__global__ __launch_bounds__(256) void attr_h_kernel(
    const float* __restrict__ attr_emb, const _Float16* __restrict__ Wp,
    _Float16* __restrict__ Vp) {
    int wave = threadIdx.x >> 6, lane = threadIdx.x & 63;
    int m = lane & 15, quad = lane >> 4;
    int j0 = (blockIdx.x * 4 + wave) * 16;  // grid = 80 -> j0 in [0, 5120)
    int j = j0 + m;
    bool valid = j < N_ATTRS;
    f32x4 acc[8];
#pragma unroll
    for (int nb = 0; nb < 8; ++nb)
#pragma unroll
        for (int t = 0; t < 4; ++t) acc[nb][t] = 0.f;
    const float* arow = attr_emb + (size_t)j * IN_F;
    for (int kk = 0; kk < IN_F / 32; ++kk) {
        f16x8 afrag;
        if (valid) {
            float4 ra = *reinterpret_cast<const float4*>(arow + kk * 32 + quad * 8);
            float4 rb = *reinterpret_cast<const float4*>(arow + kk * 32 + quad * 8 + 4);
            afrag[0] = (_Float16)ra.x; afrag[1] = (_Float16)ra.y;
            afrag[2] = (_Float16)ra.z; afrag[3] = (_Float16)ra.w;
            afrag[4] = (_Float16)rb.x; afrag[5] = (_Float16)rb.y;
            afrag[6] = (_Float16)rb.z; afrag[7] = (_Float16)rb.w;
        } else {
#pragma unroll
            for (int t = 0; t < 8; ++t) afrag[t] = (_Float16)0.f;
        }
        const _Float16* wbase = Wp + (size_t)(kk * 8) * 64 * 8;
#pragma unroll
        for (int nb = 0; nb < 8; ++nb) {
            f16x8 bfrag;
            __builtin_memcpy(&bfrag, wbase + (nb * 64 + lane) * 8, 16);
            acc[nb] = __builtin_amdgcn_mfma_f32_16x16x32_f16(afrag, bfrag, acc[nb], 0, 0, 0);
        }
    }
#pragma unroll
    for (int nb = 0; nb < 8; ++nb) {
#pragma unroll
        for (int reg = 0; reg < 4; ++reg) {
            int jr = j0 + quad * 4 + reg;
            int n = nb * 16 + m;
            float v = (jr < N_ATTRS) ? acc[nb][reg] : 0.f;  // zero the K padding
            size_t idx = ((size_t)((jr >> 5) * 8 + nb) * 64 +
                          (((jr >> 3) & 3) * 16 + m)) * 8 + (jr & 7);
            Vp[idx] = (_Float16)v;
        }
    }
}

// ---------------------------------------------------------------------------
// Kernel 4 (main), m97-style barrier-enforced pipeline (compiler-proof):
//  - block = 32 rows (grid 625 = 20000/32 exact), 4 waves
//  - wave w: row group (w>>1)*16, kstep parity w&1 (even/odd ksteps)
//  - superstep = 2 ksteps (64 attrs). Per superstep, async global_load_lds:
//      Vp 16 KB (coop, contiguous), feat 8 KB (per-wave, A-frag order:
//      dest = lane*16 -> conflict-free ds_read_b128), wh2 256 B
//    into LDS double buffer; ONE barrier; compute phase reads LDS only.
//  - loads for superstep s+1 fly during compute of s; the barrier drains
//    them one full phase later. The scheduler cannot sink DMA past barriers.
//  - LDS 48.5 KB -> 3 blocks/CU (12 waves/CU, m97-grade latency cover)
// ---------------------------------------------------------------------------
__global__ __launch_bounds__(256, 3) void attn_kernel(
    const int* __restrict__ feat, const float* __restrict__ wh1,
    const float* __restrict__ wh2, const float* __restrict__ maxwh2,
    const _Float16* __restrict__ Vp, float* __restrict__ out) {
    __shared__ __align__(16) char lds[49664];   // vbuf 2x16K | fbuf 2x8K | wbuf 2x256
    __shared__ float rsums[32];

    int wave = threadIdx.x >> 6, lane = threadIdx.x & 63;
    int m = lane & 15, quad = lane >> 4;
    int i0 = blockIdx.x * 32;
    int rg = (wave >> 1) * 16;         // row-group base (0 or 16)
    int half = wave & 1;               // kstep parity

    float wh1i = wh1[i0 + rg + m];     // scaled by log2(e)
    float emax = wh1i + maxwh2[0];
    float Mi = fmaxf(emax, 0.2f * emax) - 12.f;   // f16 P in (0, 4096]

    f32x4 acc[8];
#pragma unroll
    for (int nb = 0; nb < 8; ++nb)
#pragma unroll
        for (int t = 0; t < 4; ++t) acc[nb][t] = 0.f;
    float s = 0.f;

    char* vbuf0 = lds;                 // 16384 per buffer
    char* fbuf0 = lds + 32768;         // 8192 per buffer
    char* wbuf0 = lds + 49152;         // 256 per buffer

    const char* featb = (const char*)feat;
    size_t frow_off = (size_t)(i0 + rg + m) * N_ATTRS * 4;   // this lane's row

    // ---- staging for superstep ss into buffer b (async DMA, no waits) ----
    auto stage = [&](int ss, int b) {
        // Vp: 16 KB contiguous, each wave 4 KB
        const char* vsrc = (const char*)Vp + (size_t)ss * 16384 + wave * 4096 + lane * 16;
        char* vdst = vbuf0 + b * 16384 + wave * 4096;
#pragma unroll
        for (int q = 0; q < 4; ++q) async16(vdst + q * 1024, vsrc + q * 1024);
        // feat: this wave's kstep, A-frag order (lane m=row, quad*8 attrs)
        int kbase = (2 * ss + half) * 32;
        char* fdst = fbuf0 + b * 8192 + wave * 2048;
#pragma unroll
        for (int h = 0; h < 2; ++h) {
            int a = kbase + quad * 8 + h * 4;
            a = min(a, N_ATTRS - 4);               // tail clamp (wh2 NEGBIG masks)
            async16(fdst + h * 1024, featb + frow_off + (size_t)a * 4);
        }
        // wh2: 64 floats for the superstep (wave 0, lanes 0-15)
        if (wave == 0 && lane < 16)
            async16(wbuf0 + b * 256, (const char*)(wh2 + ss * 64) + lane * 16);
    };

    stage(0, 0);
    __syncthreads();

    for (int ss = 0; ss < NSS; ++ss) {
        int cur = ss & 1;
        if (ss + 1 < NSS) stage(ss + 1, cur ^ 1);   // flies during compute of ss

        // ---- compute phase: LDS only ----
        char* wb = wbuf0 + cur * 256 + half * 128 + quad * 32;
        float4 wva = *reinterpret_cast<const float4*>(wb);
        float4 wvb = *reinterpret_cast<const float4*>(wb + 16);
        char* fb = fbuf0 + cur * 8192 + wave * 2048 + lane * 16;
        i32x4 fA = *reinterpret_cast<const i32x4*>(fb);
        i32x4 fB = *reinterpret_cast<const i32x4*>(fb + 1024);

        int   fi[8] = {fA.x, fA.y, fA.z, fA.w, fB.x, fB.y, fB.z, fB.w};
        float wv[8] = {wva.x, wva.y, wva.z, wva.w, wvb.x, wvb.y, wvb.z, wvb.w};
        f16x8 afrag;
#pragma unroll
        for (int t = 0; t < 8; ++t) {
            float e = wh1i + wv[t];                // pad attrs: e ~ -1e30
            float l = fmaxf(e, 0.2f * e);
            float p = fast_exp2(l - Mi);           // pad: exp2(-huge) = 0
            p = (fi[t] > 0) ? p : 0.f;
            _Float16 ph = (_Float16)p;
            s += (float)ph;                        // sum quantized p
            afrag[t] = ph;
        }

        char* vb = vbuf0 + cur * 16384 + half * 8192;
#pragma unroll
        for (int nb = 0; nb < 8; ++nb) {
            f16x8 bfrag = *reinterpret_cast<const f16x8*>(vb + nb * 1024 + lane * 16);
            acc[nb] = __builtin_amdgcn_mfma_f32_16x16x32_f16(afrag, bfrag, acc[nb], 0, 0, 0);
        }

        __syncthreads();   // drains s+1 staging; protects buffer swap
    }

    // ---- row sums for this wave's ksteps (rows rg..rg+15) ----
    s += __shfl_xor(s, 16, 64);
    s += __shfl_xor(s, 32, 64);

    // ---- combine kstep-parity pairs; accs overlay on vbuf (16 KB) ----
    float* accp = (float*)lds;   // [group][16][128]
    if (half == 0) {
#pragma unroll
        for (int nb = 0; nb < 8; ++nb)
#pragma unroll
            for (int reg = 0; reg < 4; ++reg)
                accp[(rg + quad * 4 + reg) * 128 + nb * 16 + m] = acc[nb][reg];
        if (lane < 16) rsums[rg + lane] = s;
    }
    __syncthreads();
    if (half == 1) {
#pragma unroll
        for (int nb = 0; nb < 8; ++nb)
#pragma unroll
            for (int reg = 0; reg < 4; ++reg)
                accp[(rg + quad * 4 + reg) * 128 + nb * 16 + m] += acc[nb][reg];
        if (lane < 16) rsums[rg + lane] += s;
    }
    __syncthreads();

    // ---- normalize, ELU, store fp32 (32 x 128) ----
    for (int o = threadIdx.x; o < 32 * 128; o += 256) {
        int lr = o >> 7, n = o & 127;
        float v = accp[lr * 128 + n];
        float rs = rsums[lr];
        rs = (rs > 0.f) ? rs : 1.f;
        float h = v / rs;
        float ov = (h > 0.f) ? h : (fast_exp2(h * LOG2E) - 1.f);
        out[(size_t)(i0 + lr) * OUT_F + n] = ov;
    }
}

// ---------------------------------------------------------------------------
extern "C" void kernel_launch(void* const* d_in, const int* in_sizes, int n_in,
                              void* d_out, int out_size, void* d_ws, size_t ws_size,
                              hipStream_t stream) {
    const float* node_emb = (const float*)d_in[0];  // fp32 [20000,512]
    const float* attr_emb = (const float*)d_in[1];  // fp32 [5000,512]
    const int*   feat     = (const int*)d_in[2];    // int32 [20000,5000]
    const float* W        = (const float*)d_in[3];  // fp32 [512,128]
    const float* a        = (const float*)d_in[4];  // fp32 [256,1]
    float*       out      = (float*)d_out;          // fp32 [20000,128]

    char* ws = (char*)d_ws;
    float*    Wa1 = (float*)(ws + 0);          // 512 f32
    float*    Wa2 = (float*)(ws + 4096);       // 512 f32
    float*    wh1 = (float*)(ws + 8192);       // 20000 f32 (ends 88192)
    float*    wh2 = (float*)(ws + 90112);      // 5376 f32 incl. NEGBIG pad (ends 111616)
    float*    mx  = (float*)(ws + 111616);     // 1 f32
    _Float16* Wp  = (_Float16*)(ws + 131072);  // 65536 f16 (ends 262144)
    _Float16* Vp  = (_Float16*)(ws + 262144);  // 5120*128 f16 (ends 1572864)

    prep_kernel<<<64, 256, 0, stream>>>(W, a, Wa1, Wa2, Wp);
    wh_kernel<<<6250, 256, 0, stream>>>(node_emb, attr_emb, Wa1, Wa2, wh1, wh2);
    max_kernel<<<1, 256, 0, stream>>>(wh2, mx);
    attr_h_kernel<<<80, 256, 0, stream>>>(attr_emb, Wp, Vp);
    attn_kernel<<<625, 256, 0, stream>>>(feat, wh1, wh2, mx, Vp, out);
}